// Round 8
// baseline (1328.511 us; speedup 1.0000x reference)
//
#include <hip/hip_runtime.h>
#include <stdint.h>
#include <stddef.h>

#define NL   4
#define CBC  256
#define DCH  512
#define KW   3
#define BATCH 16
#define TT   4096
#define BT   (BATCH*TT)
#define EPSB 1e-5f

typedef __bf16 bf16_t;
typedef __attribute__((ext_vector_type(8))) __bf16 bf16x8;
typedef __attribute__((ext_vector_type(4))) float f32x4;
typedef __attribute__((ext_vector_type(8))) unsigned short us8;
typedef __attribute__((ext_vector_type(4))) unsigned short us4;

static __device__ __forceinline__ unsigned short f2bf(float f) {
    union { float f; uint32_t u; } v; v.f = f;
    uint32_t u = v.u;
    u += 0x7FFFu + ((u >> 16) & 1u);   // RNE
    return (unsigned short)(u >> 16);
}
static __device__ __forceinline__ float bf2f(unsigned short b) {
    union { uint32_t u; float f; } v; v.u = ((uint32_t)b) << 16;
    return v.f;
}
static __device__ __forceinline__ bf16x8 as_bf16x8(us8 u) {
    return __builtin_bit_cast(bf16x8, u);
}
static __device__ __forceinline__ float signf_(float w) {
    return (w > 0.f) ? 1.f : ((w < 0.f) ? -1.f : 0.f);
}

typedef __attribute__((address_space(1))) void as1_void;
typedef __attribute__((address_space(3))) void as3_void;
static __device__ __forceinline__ void gload_lds16(const unsigned short* g, unsigned short* l) {
    // 16B per lane, wave-uniform LDS base + lane*16 (guide §5: width=16 verified m97)
    __builtin_amdgcn_global_load_lds((as1_void*)g, (as3_void*)l, 16, 0, 0);
}

// ---------------------------------------------------------------------------
// Weight prep: sign(w1) -> bf16 [L][D][CB]; sign(wd) -> f32 [L][D][3]
// ---------------------------------------------------------------------------
__global__ void prep_kernel(const float* __restrict__ w1, const float* __restrict__ wd,
                            unsigned short* __restrict__ W1S, float* __restrict__ WDS) {
    const int NW1 = NL * DCH * CBC;
    const int NWD = NL * DCH * KW;
    int idx = blockIdx.x * 256 + threadIdx.x;
    if (idx < NW1) {
        W1S[idx] = f2bf(signf_(w1[idx]));
    } else if (idx < NW1 + NWD) {
        int j = idx - NW1;
        WDS[j] = signf_(wd[j]);
    }
}

// ---------------------------------------------------------------------------
// Input transpose: x [B][CB][T] f32  ->  XA [B*T][CB] bf16
// ---------------------------------------------------------------------------
__global__ void transpose_in(const float* __restrict__ x, unsigned short* __restrict__ XA) {
    __shared__ unsigned short tile[64][72];
    const int t0 = blockIdx.x * 64, c0 = blockIdx.y * 64, b = blockIdx.z;
    const int tid = threadIdx.x;
    {
        const int cl = tid >> 2;
        const int tl = (tid & 3) * 16;
        const float* src = x + ((size_t)(b * CBC + c0 + cl)) * TT + t0 + tl;
        #pragma unroll
        for (int u = 0; u < 16; u += 4) {
            float4 f = *(const float4*)(src + u);
            tile[cl][tl + u + 0] = f2bf(f.x);
            tile[cl][tl + u + 1] = f2bf(f.y);
            tile[cl][tl + u + 2] = f2bf(f.z);
            tile[cl][tl + u + 3] = f2bf(f.w);
        }
    }
    __syncthreads();
    {
        const int tr = tid >> 2;
        const int cc = (tid & 3) * 16;
        us8 o0, o1;
        #pragma unroll
        for (int e = 0; e < 8; ++e) { o0[e] = tile[cc + e][tr]; o1[e] = tile[cc + 8 + e][tr]; }
        unsigned short* dst = XA + ((size_t)(b * TT + t0 + tr)) * CBC + c0 + cc;
        *(us8*)dst = o0;
        *(us8*)(dst + 8) = o1;
    }
}

// ---------------------------------------------------------------------------
// GEMM: out[n][m] = sum_k A[m][k] * B[n][k] (+bias, optional PReLU)
// 128m x 256t tile, BK=32, 8 waves (512 threads). Same catalog-verified
// 2-phase double-buffer sync as rounds 3/6 (parameter change only — r7's
// counted-vmcnt was neutral and is retired): per iter {STAGE(next) ->
// ds_read(cur) -> MFMA -> vmcnt(0) -> s_barrier}, sched_barrier(0) pins
// (rule #18). Rationale: the 2-phase pays a fixed stage+drain+barrier toll
// PER ITERATION (m233); doubling tile area halves total block-iters
// (GEMM1: 16384 -> 8192) and staged volume (268 -> 197 MB) at unchanged
// per-wave iter cost (3 gload_lds + 8 ds_read + 16 MFMA, same 4x4 acc).
// LDS 2 x 24KB = 48KB -> 3 blocks/CU = 24 waves/CU.
// Wave w: wm=w&1 (m-half), wn=w>>1 (t-quarter, 64t each).
// LDS XOR swizzle both-sides (rule #21). Grid: 1D, bijective XCD-chunked
// swizzle, m-tiles innermost (L2 B-reuse).
// Epilogue: stats pre-pass (shuffle+LDS), then TWO 128-t sout passes
// (barrier-bracketed, uniform control flow) reusing the 34KB union buffer.
// ---------------------------------------------------------------------------
template<int K, int NMT, bool PRELU, bool FINAL, bool STATS>
__global__ __launch_bounds__(512, 6)
void gemm_kernel(const unsigned short* __restrict__ A,
                 const unsigned short* __restrict__ Bact,
                 const float* __restrict__ bias,
                 const float* __restrict__ aptr,
                 unsigned short* __restrict__ Obf,
                 float* __restrict__ Ofin,
                 const float* __restrict__ resid,
                 float* __restrict__ sums, float* __restrict__ sqs,
                 int M) {
    __shared__ union {
        unsigned short stage[2][12288];      // [buf][ A:128x32 | B:256x32 ] = 48KB
        unsigned short sout[128 * 136];      // epilogue transpose (34KB)
    } sm;
    __shared__ float sstat[2][8][64];        // [sum/sq][wave][ch_local]

    const int tid = threadIdx.x;

    // bijective XCD-chunked swizzle (nwg % 8 == 0 always here, m204)
    const int nwg = NMT * (TT / 256) * BATCH;
    const int orig = blockIdx.x;
    const int logical = (orig & 7) * (nwg >> 3) + (orig >> 3);
    const int mt = logical % NMT;            // m-tile innermost -> same-XCD B reuse
    const int rest = logical / NMT;
    const int tt = rest & 15;                // TT/256 = 16 t-tiles
    const int bz = rest >> 4;
    const int t0 = tt * 256;
    const int m0 = mt * 128;
    const size_t n0 = (size_t)bz * TT + t0;

    const int lane = tid & 63;
    const int w    = tid >> 6;               // 8 waves
    const int wm = w & 1, wn = w >> 1;       // wn in [0,4): 64-t quarter
    const int l16 = lane & 15, q = lane >> 4;

    // staging: thread tid covers tile row tid>>2 (128 rows), swizzled 16B chunk
    const int rS = tid >> 2;
    const int cS = ((tid & 3) ^ ((tid >> 3) & 3)) * 8;   // chunk ^ ((row>>1)&3)
    const unsigned short* gA  = A + (size_t)(m0 + rS) * K + cS;
    const unsigned short* gB0 = Bact + (n0 + rS) * K + cS;
    const unsigned short* gB1 = Bact + (n0 + 128 + rS) * K + cS;
    const int wofs = w << 9;                  // per-wave 512-short (1KB) slice

    auto STAGE = [&](int step, int buf) {
        const int k0 = step * 32;
        unsigned short* sb = &sm.stage[buf][0];
        gload_lds16(gA  + k0, sb + wofs);            // A rows 0-127
        gload_lds16(gB0 + k0, sb + 4096 + wofs);     // B rows 0-127
        gload_lds16(gB1 + k0, sb + 8192 + wofs);     // B rows 128-255
    };

    f32x4 acc[4][4];
    #pragma unroll
    for (int i = 0; i < 4; ++i)
        #pragma unroll
        for (int j = 0; j < 4; ++j)
            acc[i][j] = (f32x4){0.f, 0.f, 0.f, 0.f};

    // read-side swizzle: ((row)>>1)&3 == (l16>>1)&3 for all fragment rows
    const int csw = (q ^ ((l16 >> 1) & 3)) << 3;

    constexpr int NK = K / 32;
    // prologue: stage tile 0, publish
    STAGE(0, 0);
    asm volatile("s_waitcnt vmcnt(0)" ::: "memory");
    __builtin_amdgcn_s_barrier();
    __builtin_amdgcn_sched_barrier(0);

    #pragma unroll
    for (int k = 0; k < NK; ++k) {
        const int cur = k & 1;
        // issue next-tile loads FIRST (latency hides under compute below)
        if (k + 1 < NK) STAGE(k + 1, cur ^ 1);
        const unsigned short* sb = &sm.stage[cur][0];
        bf16x8 af[4], bfv[4];
        #pragma unroll
        for (int i = 0; i < 4; ++i)
            af[i] = as_bf16x8(*(const us8*)(sb + (wm * 64 + i * 16 + l16) * 32 + csw));
        #pragma unroll
        for (int j = 0; j < 4; ++j)
            bfv[j] = as_bf16x8(*(const us8*)(sb + 4096 + (wn * 64 + j * 16 + l16) * 32 + csw));
        #pragma unroll
        for (int i = 0; i < 4; ++i)
            #pragma unroll
            for (int j = 0; j < 4; ++j)
                acc[i][j] = __builtin_amdgcn_mfma_f32_16x16x32_bf16(af[i], bfv[j], acc[i][j], 0, 0, 0);
        // publish next tile: own loads landed, then barrier => all waves' landed
        if (k + 1 < NK) {
            asm volatile("s_waitcnt vmcnt(0)" ::: "memory");
            __builtin_amdgcn_sched_barrier(0);
        }
        __builtin_amdgcn_s_barrier();
        __builtin_amdgcn_sched_barrier(0);
    }
    // loop's final barrier: all waves' last ds_reads retired, vmcnt drained
    // since iter NK-2 => sout (unioned with stage) safe to write.

    float alpha = 0.f;
    if constexpr (PRELU) alpha = aptr[0];

    if constexpr (FINAL) {
        #pragma unroll
        for (int i = 0; i < 4; ++i) {
            const int m_l = wm * 64 + i * 16 + q * 4;
            float bia[4];
            #pragma unroll
            for (int rg = 0; rg < 4; ++rg) bia[rg] = bias[m0 + m_l + rg];
            #pragma unroll
            for (int j = 0; j < 4; ++j) {
                const int n_l = wn * 64 + j * 16 + l16;   // [0,256)
                const int t = t0 + n_l;
                #pragma unroll
                for (int rg = 0; rg < 4; ++rg) {
                    float v = acc[i][j][rg] + bia[rg];
                    size_t oidx = ((size_t)(bz * CBC + m0 + m_l + rg)) * TT + t;
                    Ofin[oidx] = v + resid[oidx];
                }
            }
        }
    } else {
        // stats pre-pass (independent of sout passes)
        if constexpr (STATS) {
            #pragma unroll
            for (int i = 0; i < 4; ++i) {
                const int m_l = wm * 64 + i * 16 + q * 4;
                float bia[4];
                #pragma unroll
                for (int rg = 0; rg < 4; ++rg) bia[rg] = bias[m0 + m_l + rg];
                #pragma unroll
                for (int rg = 0; rg < 4; ++rg) {
                    float sv = 0.f, sq2 = 0.f;
                    #pragma unroll
                    for (int j = 0; j < 4; ++j) {
                        float v = acc[i][j][rg] + bia[rg];
                        if (PRELU) v = (v >= 0.f) ? v : alpha * v;
                        sv += v; sq2 += v * v;
                    }
                    #pragma unroll
                    for (int msk = 1; msk < 16; msk <<= 1) {
                        sv  += __shfl_xor(sv,  msk, 64);
                        sq2 += __shfl_xor(sq2, msk, 64);
                    }
                    if (l16 == 0) {
                        const int cl = i * 16 + q * 4 + rg;   // channel local to wm
                        sstat[0][w][cl] = sv;
                        sstat[1][w][cl] = sq2;
                    }
                }
            }
        }
        // two 128-t sout passes; pass p handled by waves with wn>>1 == p
        #pragma unroll
        for (int p = 0; p < 2; ++p) {
            if ((wn >> 1) == p) {
                #pragma unroll
                for (int i = 0; i < 4; ++i) {
                    const int m_l = wm * 64 + i * 16 + q * 4;
                    float bia[4];
                    #pragma unroll
                    for (int rg = 0; rg < 4; ++rg) bia[rg] = bias[m0 + m_l + rg];
                    #pragma unroll
                    for (int j = 0; j < 4; ++j) {
                        const int n_l = (wn & 1) * 64 + j * 16 + l16;   // [0,128)
                        us4 pkv;
                        #pragma unroll
                        for (int rg = 0; rg < 4; ++rg) {
                            float v = acc[i][j][rg] + bia[rg];
                            if (PRELU) v = (v >= 0.f) ? v : alpha * v;
                            pkv[rg] = f2bf(v);
                        }
                        *(us4*)&sm.sout[n_l * 136 + m_l] = pkv;
                    }
                }
            }
            __syncthreads();
            {
                const int rr = tid >> 4;               // [0,32)
                const int c8 = (tid & 15) * 8;
                #pragma unroll
                for (int pp = 0; pp < 4; ++pp) {
                    const int n_l = pp * 32 + rr;
                    us8 v = *(const us8*)&sm.sout[n_l * 136 + c8];
                    *(us8*)(Obf + (n0 + p * 128 + n_l) * M + m0 + c8) = v;
                }
            }
            __syncthreads();   // before next pass overwrites sout
        }
        if constexpr (STATS) {
            if (tid < 128) {
                const int wmc = tid >> 6, cl = tid & 63;
                float S = 0.f, Q = 0.f;
                #pragma unroll
                for (int wq = 0; wq < 4; ++wq) {
                    S += sstat[0][wq * 2 + wmc][cl];
                    Q += sstat[1][wq * 2 + wmc][cl];
                }
                atomicAdd(&sums[m0 + tid], S);
                atomicAdd(&sqs[m0 + tid], Q);
            }
        }
    }
}

// ---------------------------------------------------------------------------
// Depthwise dilated causal conv + bias + PReLU, fused Z-stats.
// UNCHANGED from round 6 (channel-split grid + 16B/lane us8 layout,
// verified). Steady blocks use the exact BN1 fold (wk in {+-1,0}).
// grid = (TT/64, 2, BATCH), block 256.
// ---------------------------------------------------------------------------
__global__ __launch_bounds__(256)
void dwconv_kernel(const unsigned short* __restrict__ Y,
                   const float* __restrict__ sums1, const float* __restrict__ sqs1,
                   const float* __restrict__ g1, const float* __restrict__ be1,
                   const float* __restrict__ wds, const float* __restrict__ bd,
                   const float* __restrict__ a2p, int dil,
                   unsigned short* __restrict__ Z,
                   float* __restrict__ sums2, float* __restrict__ sqs2) {
    __shared__ float ssum[4][256];
    __shared__ float ssq[4][256];
    const int b = blockIdx.z;
    const int half = blockIdx.y;
    const int t0 = blockIdx.x * 64;
    const int tid = threadIdx.x;
    const int w = tid >> 6;
    const int lane = tid & 63;
    const int r = lane >> 5;              // row sub-index within wave (0/1)
    const int cl = (lane & 31) * 8;       // channel local to this half
    const int c0 = half * 256 + cl;       // global channel base (8 channels)
    const float alpha = a2p[0];

    // fused BN1 finalize (per-lane, 8 channels) + raw weights
    float s8[8], sh8[8], wv0[8], wv1[8], wv2[8], bb8[8];
    const float inv = 1.f / (float)BT;
    #pragma unroll
    for (int e = 0; e < 8; ++e) {
        const int d = c0 + e;
        float mean = sums1[d] * inv;
        float var = sqs1[d] * inv - mean * mean;
        float sc = g1[d] * rsqrtf(var + EPSB);
        s8[e] = sc;
        sh8[e] = be1[d] - mean * sc;
        wv0[e] = wds[d * 3 + 0]; wv1[e] = wds[d * 3 + 1]; wv2[e] = wds[d * 3 + 2];
        bb8[e] = bd[d];
    }

    float asum[8], asq[8];
    #pragma unroll
    for (int e = 0; e < 8; ++e) { asum[e] = 0.f; asq[e] = 0.f; }

    if (blockIdx.x == 0) {
        // boundary block: conditional taps (t < 2*dil possible), unfolded BN
        for (int it = 0; it < 8; ++it) {
            const int t = it * 8 + 2 * w + r;
            const size_t base = ((size_t)b * TT + t) * DCH + c0;
            float acc[8];
            {
                us8 y0 = *(const us8*)&Y[base];
                #pragma unroll
                for (int e = 0; e < 8; ++e)
                    acc[e] = wv2[e] * (s8[e] * bf2f(y0[e]) + sh8[e]) + bb8[e];
            }
            if (t >= dil) {
                us8 y1 = *(const us8*)&Y[base - (size_t)dil * DCH];
                #pragma unroll
                for (int e = 0; e < 8; ++e)
                    acc[e] += wv1[e] * (s8[e] * bf2f(y1[e]) + sh8[e]);
            }
            if (t >= 2 * dil) {
                us8 y2 = *(const us8*)&Y[base - (size_t)(2 * dil) * DCH];
                #pragma unroll
                for (int e = 0; e < 8; ++e)
                    acc[e] += wv0[e] * (s8[e] * bf2f(y2[e]) + sh8[e]);
            }
            us8 o;
            #pragma unroll
            for (int e = 0; e < 8; ++e) {
                float v = acc[e];
                v = (v >= 0.f) ? v : alpha * v;
                asum[e] += v; asq[e] += v * v;
                o[e] = f2bf(v);
            }
            *(us8*)&Z[base] = o;
        }
    } else {
        // steady blocks: exact BN fold (w = +-1/0), unconditional taps
        float W0s[8], W1s[8], W2s[8], shall[8];
        #pragma unroll
        for (int e = 0; e < 8; ++e) {
            W0s[e] = wv0[e] * s8[e];
            W1s[e] = wv1[e] * s8[e];
            W2s[e] = wv2[e] * s8[e];
            shall[e] = (wv0[e] + wv1[e] + wv2[e]) * sh8[e] + bb8[e];
        }
        const size_t d1 = (size_t)dil * DCH, d2 = 2 * d1;
        for (int it = 0; it < 8; ++it) {
            const int t = t0 + it * 8 + 2 * w + r;
            const size_t base = ((size_t)b * TT + t) * DCH + c0;
            us8 y0 = *(const us8*)&Y[base];
            us8 y1 = *(const us8*)&Y[base - d1];
            us8 y2 = *(const us8*)&Y[base - d2];
            us8 o;
            #pragma unroll
            for (int e = 0; e < 8; ++e) {
                float v = W2s[e] * bf2f(y0[e]) + W1s[e] * bf2f(y1[e])
                        + W0s[e] * bf2f(y2[e]) + shall[e];
                v = (v >= 0.f) ? v : alpha * v;
                asum[e] += v; asq[e] += v * v;
                o[e] = f2bf(v);
            }
            *(us8*)&Z[base] = o;
        }
    }

    // combine the two row-groups (lane l and l+32 hold the same channels)
    #pragma unroll
    for (int e = 0; e < 8; ++e) {
        asum[e] += __shfl_xor(asum[e], 32, 64);
        asq[e]  += __shfl_xor(asq[e], 32, 64);
    }
    if (lane < 32) {
        #pragma unroll
        for (int e = 0; e < 8; ++e) { ssum[w][cl + e] = asum[e]; ssq[w][cl + e] = asq[e]; }
    }
    __syncthreads();
    {
        const int ch = tid;   // 0..255 (one channel per thread, local to half)
        float S = ssum[0][ch] + ssum[1][ch] + ssum[2][ch] + ssum[3][ch];
        float Q = ssq[0][ch] + ssq[1][ch] + ssq[2][ch] + ssq[3][ch];
        atomicAdd(&sums2[half * 256 + ch], S);
        atomicAdd(&sqs2[half * 256 + ch], Q);
    }
}

// ---------------------------------------------------------------------------
// Fold BN2 into GEMM2 weights (BN2 finalize fused in):
// sc2/shf2 computed per-thread from raw sums2/sqs2.
// W2eff[c][d] = sign(w2[c][d]) * sc2[d] (bf16)
// b2eff[c] = b2[c] + sum_d sign(w2[c][d]) * shf2[d]
// ---------------------------------------------------------------------------
__global__ void fold_kernel(const float* __restrict__ w2,
                            const float* __restrict__ sums2, const float* __restrict__ sqs2,
                            const float* __restrict__ g2, const float* __restrict__ be2,
                            const float* __restrict__ b2,
                            unsigned short* __restrict__ W2E, float* __restrict__ B2E) {
    __shared__ float red[256];
    const int c = blockIdx.x, tid = threadIdx.x;
    const float inv = 1.f / (float)BT;
    float part = 0.f;
    for (int d = tid; d < DCH; d += 256) {
        float mean = sums2[d] * inv;
        float var = sqs2[d] * inv - mean * mean;
        float sc = g2[d] * rsqrtf(var + EPSB);
        float shf = be2[d] - mean * sc;
        float w = w2[(size_t)c * DCH + d];
        float sgn = signf_(w);
        W2E[(size_t)c * DCH + d] = f2bf(sgn * sc);
        part += sgn * shf;
    }
    red[tid] = part;
    __syncthreads();
    for (int off = 128; off > 0; off >>= 1) {
        if (tid < off) red[tid] += red[tid + off];
        __syncthreads();
    }
    if (tid == 0) B2E[c] = b2[c] + red[0];
}

// ---------------------------------------------------------------------------
extern "C" void kernel_launch(void* const* d_in, const int* in_sizes, int n_in,
                              void* d_out, int out_size, void* d_ws, size_t ws_size,
                              hipStream_t stream) {
    const float* x   = (const float*)d_in[0];
    const float* w1  = (const float*)d_in[1];
    const float* b1  = (const float*)d_in[2];
    const float* a1  = (const float*)d_in[3];
    const float* g1  = (const float*)d_in[4];
    const float* be1 = (const float*)d_in[5];
    const float* wd  = (const float*)d_in[6];
    const float* bd  = (const float*)d_in[7];
    const float* a2  = (const float*)d_in[8];
    const float* g2  = (const float*)d_in[9];
    const float* be2 = (const float*)d_in[10];
    const float* w2  = (const float*)d_in[11];
    const float* b2  = (const float*)d_in[12];
    float* out = (float*)d_out;

    char* ws = (char*)d_ws;
    size_t off = 0;
    auto alloc = [&](size_t bytes) -> void* {
        void* p = ws + off;
        off += (bytes + 255) & ~(size_t)255;
        return p;
    };
    unsigned short* XA  = (unsigned short*)alloc((size_t)BT * CBC * 2);
    unsigned short* Y   = (unsigned short*)alloc((size_t)BT * DCH * 2);
    unsigned short* Z   = (unsigned short*)alloc((size_t)BT * DCH * 2);
    unsigned short* W1S = (unsigned short*)alloc((size_t)NL * DCH * CBC * 2);
    float* WDS          = (float*)alloc((size_t)NL * DCH * KW * 4);
    unsigned short* W2E = (unsigned short*)alloc((size_t)CBC * DCH * 2);
    float* B2E          = (float*)alloc((size_t)CBC * 4);
    // per-layer stat buffers: [sums1|sqs1|sums2|sqs2] x NL x 512, zeroed once
    float* stats = (float*)alloc((size_t)4 * NL * 512 * 4);
    float* sums1 = stats + 0 * NL * 512;
    float* sqs1  = stats + 1 * NL * 512;
    float* sums2 = stats + 2 * NL * 512;
    float* sqs2  = stats + 3 * NL * 512;

    (void)hipMemsetAsync(stats, 0, (size_t)4 * NL * 512 * 4, stream);

    {
        const int NTOT = NL * DCH * CBC + NL * DCH * KW;
        prep_kernel<<<(NTOT + 255) / 256, 256, 0, stream>>>(w1, wd, W1S, WDS);
    }
    transpose_in<<<dim3(TT / 64, CBC / 64, BATCH), 256, 0, stream>>>(x, XA);

    const int NWG1 = (DCH / 128) * (TT / 256) * BATCH;   // 4*16*16 = 1024
    const int NWG2 = (CBC / 128) * (TT / 256) * BATCH;   // 2*16*16 = 512

    for (int l = 0; l < NL; ++l) {
        // 1x1 conv CB->D + bias + PReLU, fused BN1 stats
        gemm_kernel<CBC, DCH / 128, true, false, true><<<NWG1, 512, 0, stream>>>(
            W1S + (size_t)l * DCH * CBC, XA, b1 + (size_t)l * DCH, a1 + l,
            Y, nullptr, nullptr, sums1 + l * 512, sqs1 + l * 512, DCH);
        // depthwise dilated conv (BN1 finalize fused) + bias + PReLU, fused BN2 stats
        dwconv_kernel<<<dim3(TT / 64, 2, BATCH), 256, 0, stream>>>(
            Y, sums1 + l * 512, sqs1 + l * 512, g1 + (size_t)l * DCH, be1 + (size_t)l * DCH,
            WDS + (size_t)l * DCH * KW, bd + (size_t)l * DCH, a2 + l, 1 << l,
            Z, sums2 + l * 512, sqs2 + l * 512);
        // fold BN2 (finalize fused) into GEMM2 weights
        fold_kernel<<<CBC, 256, 0, stream>>>(w2 + (size_t)l * CBC * DCH,
                                             sums2 + l * 512, sqs2 + l * 512,
                                             g2 + (size_t)l * DCH, be2 + (size_t)l * DCH,
                                             b2 + (size_t)l * CBC, W2E, B2E);
        // 1x1 conv D->CB (+ residual & fp32 [B][CB][T] on final layer)
        if (l < NL - 1) {
            gemm_kernel<DCH, CBC / 128, false, false, false><<<NWG2, 512, 0, stream>>>(
                W2E, Z, B2E, nullptr, XA, nullptr, nullptr, nullptr, nullptr, CBC);
        } else {
            gemm_kernel<DCH, CBC / 128, false, true, false><<<NWG2, 512, 0, stream>>>(
                W2E, Z, B2E, nullptr, nullptr, out, x, nullptr, nullptr, CBC);
        }
    }
}

// Round 9
// 664.300 us; speedup vs baseline: 1.9999x; 1.9999x over previous
//
#include <hip/hip_runtime.h>
#include <stdint.h>
#include <stddef.h>

#define NL   4
#define CBC  256
#define DCH  512
#define KW   3
#define BATCH 16
#define TT   4096
#define BT   (BATCH*TT)
#define EPSB 1e-5f

typedef __bf16 bf16_t;
typedef __attribute__((ext_vector_type(8))) __bf16 bf16x8;
typedef __attribute__((ext_vector_type(4))) float f32x4;
typedef __attribute__((ext_vector_type(8))) unsigned short us8;
typedef __attribute__((ext_vector_type(4))) unsigned short us4;

static __device__ __forceinline__ unsigned short f2bf(float f) {
    union { float f; uint32_t u; } v; v.f = f;
    uint32_t u = v.u;
    u += 0x7FFFu + ((u >> 16) & 1u);   // RNE
    return (unsigned short)(u >> 16);
}
static __device__ __forceinline__ float bf2f(unsigned short b) {
    union { uint32_t u; float f; } v; v.u = ((uint32_t)b) << 16;
    return v.f;
}
static __device__ __forceinline__ bf16x8 as_bf16x8(us8 u) {
    return __builtin_bit_cast(bf16x8, u);
}
static __device__ __forceinline__ float signf_(float w) {
    return (w > 0.f) ? 1.f : ((w < 0.f) ? -1.f : 0.f);
}

typedef __attribute__((address_space(1))) void as1_void;
typedef __attribute__((address_space(3))) void as3_void;
static __device__ __forceinline__ void gload_lds16(const unsigned short* g, unsigned short* l) {
    // 16B per lane, wave-uniform LDS base + lane*16 (guide §5: width=16 verified m97)
    __builtin_amdgcn_global_load_lds((as1_void*)g, (as3_void*)l, 16, 0, 0);
}

// ---------------------------------------------------------------------------
// Weight prep: sign(w1) -> bf16 [L][D][CB]; sign(wd) -> f32 [L][D][3]
// ---------------------------------------------------------------------------
__global__ void prep_kernel(const float* __restrict__ w1, const float* __restrict__ wd,
                            unsigned short* __restrict__ W1S, float* __restrict__ WDS) {
    const int NW1 = NL * DCH * CBC;
    const int NWD = NL * DCH * KW;
    int idx = blockIdx.x * 256 + threadIdx.x;
    if (idx < NW1) {
        W1S[idx] = f2bf(signf_(w1[idx]));
    } else if (idx < NW1 + NWD) {
        int j = idx - NW1;
        WDS[j] = signf_(wd[j]);
    }
}

// ---------------------------------------------------------------------------
// Input transpose: x [B][CB][T] f32  ->  XA [B*T][CB] bf16
// ---------------------------------------------------------------------------
__global__ void transpose_in(const float* __restrict__ x, unsigned short* __restrict__ XA) {
    __shared__ unsigned short tile[64][72];
    const int t0 = blockIdx.x * 64, c0 = blockIdx.y * 64, b = blockIdx.z;
    const int tid = threadIdx.x;
    {
        const int cl = tid >> 2;
        const int tl = (tid & 3) * 16;
        const float* src = x + ((size_t)(b * CBC + c0 + cl)) * TT + t0 + tl;
        #pragma unroll
        for (int u = 0; u < 16; u += 4) {
            float4 f = *(const float4*)(src + u);
            tile[cl][tl + u + 0] = f2bf(f.x);
            tile[cl][tl + u + 1] = f2bf(f.y);
            tile[cl][tl + u + 2] = f2bf(f.z);
            tile[cl][tl + u + 3] = f2bf(f.w);
        }
    }
    __syncthreads();
    {
        const int tr = tid >> 2;
        const int cc = (tid & 3) * 16;
        us8 o0, o1;
        #pragma unroll
        for (int e = 0; e < 8; ++e) { o0[e] = tile[cc + e][tr]; o1[e] = tile[cc + 8 + e][tr]; }
        unsigned short* dst = XA + ((size_t)(b * TT + t0 + tr)) * CBC + c0 + cc;
        *(us8*)dst = o0;
        *(us8*)(dst + 8) = o1;
    }
}

// ---------------------------------------------------------------------------
// GEMM: out[n][m] = sum_k A[m][k] * B[n][k] (+bias, optional PReLU)
// 128m x 256t tile, BK=32, 8 waves (512 threads). Same catalog-verified
// 2-phase double-buffer sync as rounds 3/6: per iter {STAGE(next) ->
// ds_read(cur) -> MFMA -> vmcnt(0) -> s_barrier}, sched_barrier(0) pins
// (rule #18). Structure correctness-verified in round 8 (passed).
// LAUNCH BOUNDS FIX (round-8 post-mortem): (512,6) capped VGPR at ~85 and
// spilled the 64-reg accumulator to scratch (VGPR_Count=40, WRITE_SIZE
// 416MB vs 65MB output -> +350MB scratch traffic, 2.3x regression).
// (512,2) lets the allocator use ~110 VGPR -> no spill -> 4 waves/SIMD,
// 2 blocks/CU (LDS 52KB allows 3).
// LDS XOR swizzle both-sides (rule #21). Grid: 1D, bijective XCD-chunked
// swizzle, m-tiles innermost (L2 B-reuse).
// Epilogue: stats pre-pass (shuffle+LDS), then TWO 128-t sout passes
// (barrier-bracketed, uniform control flow) reusing the 34KB union buffer.
// ---------------------------------------------------------------------------
template<int K, int NMT, bool PRELU, bool FINAL, bool STATS>
__global__ __launch_bounds__(512, 2)
void gemm_kernel(const unsigned short* __restrict__ A,
                 const unsigned short* __restrict__ Bact,
                 const float* __restrict__ bias,
                 const float* __restrict__ aptr,
                 unsigned short* __restrict__ Obf,
                 float* __restrict__ Ofin,
                 const float* __restrict__ resid,
                 float* __restrict__ sums, float* __restrict__ sqs,
                 int M) {
    __shared__ union {
        unsigned short stage[2][12288];      // [buf][ A:128x32 | B:256x32 ] = 48KB
        unsigned short sout[128 * 136];      // epilogue transpose (34KB)
    } sm;
    __shared__ float sstat[2][8][64];        // [sum/sq][wave][ch_local]

    const int tid = threadIdx.x;

    // bijective XCD-chunked swizzle (nwg % 8 == 0 always here, m204)
    const int nwg = NMT * (TT / 256) * BATCH;
    const int orig = blockIdx.x;
    const int logical = (orig & 7) * (nwg >> 3) + (orig >> 3);
    const int mt = logical % NMT;            // m-tile innermost -> same-XCD B reuse
    const int rest = logical / NMT;
    const int tt = rest & 15;                // TT/256 = 16 t-tiles
    const int bz = rest >> 4;
    const int t0 = tt * 256;
    const int m0 = mt * 128;
    const size_t n0 = (size_t)bz * TT + t0;

    const int lane = tid & 63;
    const int w    = tid >> 6;               // 8 waves
    const int wm = w & 1, wn = w >> 1;       // wn in [0,4): 64-t quarter
    const int l16 = lane & 15, q = lane >> 4;

    // staging: thread tid covers tile row tid>>2 (128 rows), swizzled 16B chunk
    const int rS = tid >> 2;
    const int cS = ((tid & 3) ^ ((tid >> 3) & 3)) * 8;   // chunk ^ ((row>>1)&3)
    const unsigned short* gA  = A + (size_t)(m0 + rS) * K + cS;
    const unsigned short* gB0 = Bact + (n0 + rS) * K + cS;
    const unsigned short* gB1 = Bact + (n0 + 128 + rS) * K + cS;
    const int wofs = w << 9;                  // per-wave 512-short (1KB) slice

    auto STAGE = [&](int step, int buf) {
        const int k0 = step * 32;
        unsigned short* sb = &sm.stage[buf][0];
        gload_lds16(gA  + k0, sb + wofs);            // A rows 0-127
        gload_lds16(gB0 + k0, sb + 4096 + wofs);     // B rows 0-127
        gload_lds16(gB1 + k0, sb + 8192 + wofs);     // B rows 128-255
    };

    f32x4 acc[4][4];
    #pragma unroll
    for (int i = 0; i < 4; ++i)
        #pragma unroll
        for (int j = 0; j < 4; ++j)
            acc[i][j] = (f32x4){0.f, 0.f, 0.f, 0.f};

    // read-side swizzle: ((row)>>1)&3 == (l16>>1)&3 for all fragment rows
    const int csw = (q ^ ((l16 >> 1) & 3)) << 3;

    constexpr int NK = K / 32;
    // prologue: stage tile 0, publish
    STAGE(0, 0);
    asm volatile("s_waitcnt vmcnt(0)" ::: "memory");
    __builtin_amdgcn_s_barrier();
    __builtin_amdgcn_sched_barrier(0);

    #pragma unroll
    for (int k = 0; k < NK; ++k) {
        const int cur = k & 1;
        // issue next-tile loads FIRST (latency hides under compute below)
        if (k + 1 < NK) STAGE(k + 1, cur ^ 1);
        const unsigned short* sb = &sm.stage[cur][0];
        bf16x8 af[4], bfv[4];
        #pragma unroll
        for (int i = 0; i < 4; ++i)
            af[i] = as_bf16x8(*(const us8*)(sb + (wm * 64 + i * 16 + l16) * 32 + csw));
        #pragma unroll
        for (int j = 0; j < 4; ++j)
            bfv[j] = as_bf16x8(*(const us8*)(sb + 4096 + (wn * 64 + j * 16 + l16) * 32 + csw));
        #pragma unroll
        for (int i = 0; i < 4; ++i)
            #pragma unroll
            for (int j = 0; j < 4; ++j)
                acc[i][j] = __builtin_amdgcn_mfma_f32_16x16x32_bf16(af[i], bfv[j], acc[i][j], 0, 0, 0);
        // publish next tile: own loads landed, then barrier => all waves' landed
        if (k + 1 < NK) {
            asm volatile("s_waitcnt vmcnt(0)" ::: "memory");
            __builtin_amdgcn_sched_barrier(0);
        }
        __builtin_amdgcn_s_barrier();
        __builtin_amdgcn_sched_barrier(0);
    }
    // loop's final barrier: all waves' last ds_reads retired, vmcnt drained
    // since iter NK-2 => sout (unioned with stage) safe to write.

    float alpha = 0.f;
    if constexpr (PRELU) alpha = aptr[0];

    if constexpr (FINAL) {
        #pragma unroll
        for (int i = 0; i < 4; ++i) {
            const int m_l = wm * 64 + i * 16 + q * 4;
            float bia[4];
            #pragma unroll
            for (int rg = 0; rg < 4; ++rg) bia[rg] = bias[m0 + m_l + rg];
            #pragma unroll
            for (int j = 0; j < 4; ++j) {
                const int n_l = wn * 64 + j * 16 + l16;   // [0,256)
                const int t = t0 + n_l;
                #pragma unroll
                for (int rg = 0; rg < 4; ++rg) {
                    float v = acc[i][j][rg] + bia[rg];
                    size_t oidx = ((size_t)(bz * CBC + m0 + m_l + rg)) * TT + t;
                    Ofin[oidx] = v + resid[oidx];
                }
            }
        }
    } else {
        // stats pre-pass (independent of sout passes)
        if constexpr (STATS) {
            #pragma unroll
            for (int i = 0; i < 4; ++i) {
                const int m_l = wm * 64 + i * 16 + q * 4;
                float bia[4];
                #pragma unroll
                for (int rg = 0; rg < 4; ++rg) bia[rg] = bias[m0 + m_l + rg];
                #pragma unroll
                for (int rg = 0; rg < 4; ++rg) {
                    float sv = 0.f, sq2 = 0.f;
                    #pragma unroll
                    for (int j = 0; j < 4; ++j) {
                        float v = acc[i][j][rg] + bia[rg];
                        if (PRELU) v = (v >= 0.f) ? v : alpha * v;
                        sv += v; sq2 += v * v;
                    }
                    #pragma unroll
                    for (int msk = 1; msk < 16; msk <<= 1) {
                        sv  += __shfl_xor(sv,  msk, 64);
                        sq2 += __shfl_xor(sq2, msk, 64);
                    }
                    if (l16 == 0) {
                        const int cl = i * 16 + q * 4 + rg;   // channel local to wm
                        sstat[0][w][cl] = sv;
                        sstat[1][w][cl] = sq2;
                    }
                }
            }
        }
        // two 128-t sout passes; pass p handled by waves with wn>>1 == p
        #pragma unroll
        for (int p = 0; p < 2; ++p) {
            if ((wn >> 1) == p) {
                #pragma unroll
                for (int i = 0; i < 4; ++i) {
                    const int m_l = wm * 64 + i * 16 + q * 4;
                    float bia[4];
                    #pragma unroll
                    for (int rg = 0; rg < 4; ++rg) bia[rg] = bias[m0 + m_l + rg];
                    #pragma unroll
                    for (int j = 0; j < 4; ++j) {
                        const int n_l = (wn & 1) * 64 + j * 16 + l16;   // [0,128)
                        us4 pkv;
                        #pragma unroll
                        for (int rg = 0; rg < 4; ++rg) {
                            float v = acc[i][j][rg] + bia[rg];
                            if (PRELU) v = (v >= 0.f) ? v : alpha * v;
                            pkv[rg] = f2bf(v);
                        }
                        *(us4*)&sm.sout[n_l * 136 + m_l] = pkv;
                    }
                }
            }
            __syncthreads();
            {
                const int rr = tid >> 4;               // [0,32)
                const int c8 = (tid & 15) * 8;
                #pragma unroll
                for (int pp = 0; pp < 4; ++pp) {
                    const int n_l = pp * 32 + rr;
                    us8 v = *(const us8*)&sm.sout[n_l * 136 + c8];
                    *(us8*)(Obf + (n0 + p * 128 + n_l) * M + m0 + c8) = v;
                }
            }
            __syncthreads();   // before next pass overwrites sout
        }
        if constexpr (STATS) {
            if (tid < 128) {
                const int wmc = tid >> 6, cl = tid & 63;
                float S = 0.f, Q = 0.f;
                #pragma unroll
                for (int wq = 0; wq < 4; ++wq) {
                    S += sstat[0][wq * 2 + wmc][cl];
                    Q += sstat[1][wq * 2 + wmc][cl];
                }
                atomicAdd(&sums[m0 + tid], S);
                atomicAdd(&sqs[m0 + tid], Q);
            }
        }
    }
}

// ---------------------------------------------------------------------------
// Depthwise dilated causal conv + bias + PReLU, fused Z-stats.
// UNCHANGED from round 6 (channel-split grid + 16B/lane us8 layout,
// verified). Steady blocks use the exact BN1 fold (wk in {+-1,0}).
// grid = (TT/64, 2, BATCH), block 256.
// ---------------------------------------------------------------------------
__global__ __launch_bounds__(256)
void dwconv_kernel(const unsigned short* __restrict__ Y,
                   const float* __restrict__ sums1, const float* __restrict__ sqs1,
                   const float* __restrict__ g1, const float* __restrict__ be1,
                   const float* __restrict__ wds, const float* __restrict__ bd,
                   const float* __restrict__ a2p, int dil,
                   unsigned short* __restrict__ Z,
                   float* __restrict__ sums2, float* __restrict__ sqs2) {
    __shared__ float ssum[4][256];
    __shared__ float ssq[4][256];
    const int b = blockIdx.z;
    const int half = blockIdx.y;
    const int t0 = blockIdx.x * 64;
    const int tid = threadIdx.x;
    const int w = tid >> 6;
    const int lane = tid & 63;
    const int r = lane >> 5;              // row sub-index within wave (0/1)
    const int cl = (lane & 31) * 8;       // channel local to this half
    const int c0 = half * 256 + cl;       // global channel base (8 channels)
    const float alpha = a2p[0];

    // fused BN1 finalize (per-lane, 8 channels) + raw weights
    float s8[8], sh8[8], wv0[8], wv1[8], wv2[8], bb8[8];
    const float inv = 1.f / (float)BT;
    #pragma unroll
    for (int e = 0; e < 8; ++e) {
        const int d = c0 + e;
        float mean = sums1[d] * inv;
        float var = sqs1[d] * inv - mean * mean;
        float sc = g1[d] * rsqrtf(var + EPSB);
        s8[e] = sc;
        sh8[e] = be1[d] - mean * sc;
        wv0[e] = wds[d * 3 + 0]; wv1[e] = wds[d * 3 + 1]; wv2[e] = wds[d * 3 + 2];
        bb8[e] = bd[d];
    }

    float asum[8], asq[8];
    #pragma unroll
    for (int e = 0; e < 8; ++e) { asum[e] = 0.f; asq[e] = 0.f; }

    if (blockIdx.x == 0) {
        // boundary block: conditional taps (t < 2*dil possible), unfolded BN
        for (int it = 0; it < 8; ++it) {
            const int t = it * 8 + 2 * w + r;
            const size_t base = ((size_t)b * TT + t) * DCH + c0;
            float acc[8];
            {
                us8 y0 = *(const us8*)&Y[base];
                #pragma unroll
                for (int e = 0; e < 8; ++e)
                    acc[e] = wv2[e] * (s8[e] * bf2f(y0[e]) + sh8[e]) + bb8[e];
            }
            if (t >= dil) {
                us8 y1 = *(const us8*)&Y[base - (size_t)dil * DCH];
                #pragma unroll
                for (int e = 0; e < 8; ++e)
                    acc[e] += wv1[e] * (s8[e] * bf2f(y1[e]) + sh8[e]);
            }
            if (t >= 2 * dil) {
                us8 y2 = *(const us8*)&Y[base - (size_t)(2 * dil) * DCH];
                #pragma unroll
                for (int e = 0; e < 8; ++e)
                    acc[e] += wv0[e] * (s8[e] * bf2f(y2[e]) + sh8[e]);
            }
            us8 o;
            #pragma unroll
            for (int e = 0; e < 8; ++e) {
                float v = acc[e];
                v = (v >= 0.f) ? v : alpha * v;
                asum[e] += v; asq[e] += v * v;
                o[e] = f2bf(v);
            }
            *(us8*)&Z[base] = o;
        }
    } else {
        // steady blocks: exact BN fold (w = +-1/0), unconditional taps
        float W0s[8], W1s[8], W2s[8], shall[8];
        #pragma unroll
        for (int e = 0; e < 8; ++e) {
            W0s[e] = wv0[e] * s8[e];
            W1s[e] = wv1[e] * s8[e];
            W2s[e] = wv2[e] * s8[e];
            shall[e] = (wv0[e] + wv1[e] + wv2[e]) * sh8[e] + bb8[e];
        }
        const size_t d1 = (size_t)dil * DCH, d2 = 2 * d1;
        for (int it = 0; it < 8; ++it) {
            const int t = t0 + it * 8 + 2 * w + r;
            const size_t base = ((size_t)b * TT + t) * DCH + c0;
            us8 y0 = *(const us8*)&Y[base];
            us8 y1 = *(const us8*)&Y[base - d1];
            us8 y2 = *(const us8*)&Y[base - d2];
            us8 o;
            #pragma unroll
            for (int e = 0; e < 8; ++e) {
                float v = W2s[e] * bf2f(y0[e]) + W1s[e] * bf2f(y1[e])
                        + W0s[e] * bf2f(y2[e]) + shall[e];
                v = (v >= 0.f) ? v : alpha * v;
                asum[e] += v; asq[e] += v * v;
                o[e] = f2bf(v);
            }
            *(us8*)&Z[base] = o;
        }
    }

    // combine the two row-groups (lane l and l+32 hold the same channels)
    #pragma unroll
    for (int e = 0; e < 8; ++e) {
        asum[e] += __shfl_xor(asum[e], 32, 64);
        asq[e]  += __shfl_xor(asq[e], 32, 64);
    }
    if (lane < 32) {
        #pragma unroll
        for (int e = 0; e < 8; ++e) { ssum[w][cl + e] = asum[e]; ssq[w][cl + e] = asq[e]; }
    }
    __syncthreads();
    {
        const int ch = tid;   // 0..255 (one channel per thread, local to half)
        float S = ssum[0][ch] + ssum[1][ch] + ssum[2][ch] + ssum[3][ch];
        float Q = ssq[0][ch] + ssq[1][ch] + ssq[2][ch] + ssq[3][ch];
        atomicAdd(&sums2[half * 256 + ch], S);
        atomicAdd(&sqs2[half * 256 + ch], Q);
    }
}

// ---------------------------------------------------------------------------
// Fold BN2 into GEMM2 weights (BN2 finalize fused in):
// sc2/shf2 computed per-thread from raw sums2/sqs2.
// W2eff[c][d] = sign(w2[c][d]) * sc2[d] (bf16)
// b2eff[c] = b2[c] + sum_d sign(w2[c][d]) * shf2[d]
// ---------------------------------------------------------------------------
__global__ void fold_kernel(const float* __restrict__ w2,
                            const float* __restrict__ sums2, const float* __restrict__ sqs2,
                            const float* __restrict__ g2, const float* __restrict__ be2,
                            const float* __restrict__ b2,
                            unsigned short* __restrict__ W2E, float* __restrict__ B2E) {
    __shared__ float red[256];
    const int c = blockIdx.x, tid = threadIdx.x;
    const float inv = 1.f / (float)BT;
    float part = 0.f;
    for (int d = tid; d < DCH; d += 256) {
        float mean = sums2[d] * inv;
        float var = sqs2[d] * inv - mean * mean;
        float sc = g2[d] * rsqrtf(var + EPSB);
        float shf = be2[d] - mean * sc;
        float w = w2[(size_t)c * DCH + d];
        float sgn = signf_(w);
        W2E[(size_t)c * DCH + d] = f2bf(sgn * sc);
        part += sgn * shf;
    }
    red[tid] = part;
    __syncthreads();
    for (int off = 128; off > 0; off >>= 1) {
        if (tid < off) red[tid] += red[tid + off];
        __syncthreads();
    }
    if (tid == 0) B2E[c] = b2[c] + red[0];
}

// ---------------------------------------------------------------------------
extern "C" void kernel_launch(void* const* d_in, const int* in_sizes, int n_in,
                              void* d_out, int out_size, void* d_ws, size_t ws_size,
                              hipStream_t stream) {
    const float* x   = (const float*)d_in[0];
    const float* w1  = (const float*)d_in[1];
    const float* b1  = (const float*)d_in[2];
    const float* a1  = (const float*)d_in[3];
    const float* g1  = (const float*)d_in[4];
    const float* be1 = (const float*)d_in[5];
    const float* wd  = (const float*)d_in[6];
    const float* bd  = (const float*)d_in[7];
    const float* a2  = (const float*)d_in[8];
    const float* g2  = (const float*)d_in[9];
    const float* be2 = (const float*)d_in[10];
    const float* w2  = (const float*)d_in[11];
    const float* b2  = (const float*)d_in[12];
    float* out = (float*)d_out;

    char* ws = (char*)d_ws;
    size_t off = 0;
    auto alloc = [&](size_t bytes) -> void* {
        void* p = ws + off;
        off += (bytes + 255) & ~(size_t)255;
        return p;
    };
    unsigned short* XA  = (unsigned short*)alloc((size_t)BT * CBC * 2);
    unsigned short* Y   = (unsigned short*)alloc((size_t)BT * DCH * 2);
    unsigned short* Z   = (unsigned short*)alloc((size_t)BT * DCH * 2);
    unsigned short* W1S = (unsigned short*)alloc((size_t)NL * DCH * CBC * 2);
    float* WDS          = (float*)alloc((size_t)NL * DCH * KW * 4);
    unsigned short* W2E = (unsigned short*)alloc((size_t)CBC * DCH * 2);
    float* B2E          = (float*)alloc((size_t)CBC * 4);
    // per-layer stat buffers: [sums1|sqs1|sums2|sqs2] x NL x 512, zeroed once
    float* stats = (float*)alloc((size_t)4 * NL * 512 * 4);
    float* sums1 = stats + 0 * NL * 512;
    float* sqs1  = stats + 1 * NL * 512;
    float* sums2 = stats + 2 * NL * 512;
    float* sqs2  = stats + 3 * NL * 512;

    (void)hipMemsetAsync(stats, 0, (size_t)4 * NL * 512 * 4, stream);

    {
        const int NTOT = NL * DCH * CBC + NL * DCH * KW;
        prep_kernel<<<(NTOT + 255) / 256, 256, 0, stream>>>(w1, wd, W1S, WDS);
    }
    transpose_in<<<dim3(TT / 64, CBC / 64, BATCH), 256, 0, stream>>>(x, XA);

    const int NWG1 = (DCH / 128) * (TT / 256) * BATCH;   // 4*16*16 = 1024
    const int NWG2 = (CBC / 128) * (TT / 256) * BATCH;   // 2*16*16 = 512

    for (int l = 0; l < NL; ++l) {
        // 1x1 conv CB->D + bias + PReLU, fused BN1 stats
        gemm_kernel<CBC, DCH / 128, true, false, true><<<NWG1, 512, 0, stream>>>(
            W1S + (size_t)l * DCH * CBC, XA, b1 + (size_t)l * DCH, a1 + l,
            Y, nullptr, nullptr, sums1 + l * 512, sqs1 + l * 512, DCH);
        // depthwise dilated conv (BN1 finalize fused) + bias + PReLU, fused BN2 stats
        dwconv_kernel<<<dim3(TT / 64, 2, BATCH), 256, 0, stream>>>(
            Y, sums1 + l * 512, sqs1 + l * 512, g1 + (size_t)l * DCH, be1 + (size_t)l * DCH,
            WDS + (size_t)l * DCH * KW, bd + (size_t)l * DCH, a2 + l, 1 << l,
            Z, sums2 + l * 512, sqs2 + l * 512);
        // fold BN2 (finalize fused) into GEMM2 weights
        fold_kernel<<<CBC, 256, 0, stream>>>(w2 + (size_t)l * CBC * DCH,
                                             sums2 + l * 512, sqs2 + l * 512,
                                             g2 + (size_t)l * DCH, be2 + (size_t)l * DCH,
                                             b2 + (size_t)l * CBC, W2E, B2E);
        // 1x1 conv D->CB (+ residual & fp32 [B][CB][T] on final layer)
        if (l < NL - 1) {
            gemm_kernel<DCH, CBC / 128, false, false, false><<<NWG2, 512, 0, stream>>>(
                W2E, Z, B2E, nullptr, XA, nullptr, nullptr, nullptr, nullptr, CBC);
        } else {
            gemm_kernel<DCH, CBC / 128, false, true, false><<<NWG2, 512, 0, stream>>>(
                W2E, Z, B2E, nullptr, nullptr, out, x, nullptr, nullptr, CBC);
        }
    }
}

// Round 10
// 579.726 us; speedup vs baseline: 2.2916x; 1.1459x over previous
//
#include <hip/hip_runtime.h>
#include <stdint.h>
#include <stddef.h>

#define NL   4
#define CBC  256
#define DCH  512
#define KW   3
#define BATCH 16
#define TT   4096
#define BT   (BATCH*TT)
#define EPSB 1e-5f

typedef __bf16 bf16_t;
typedef __attribute__((ext_vector_type(8))) __bf16 bf16x8;
typedef __attribute__((ext_vector_type(4))) float f32x4;
typedef __attribute__((ext_vector_type(8))) unsigned short us8;
typedef __attribute__((ext_vector_type(4))) unsigned short us4;

static __device__ __forceinline__ unsigned short f2bf(float f) {
    union { float f; uint32_t u; } v; v.f = f;
    uint32_t u = v.u;
    u += 0x7FFFu + ((u >> 16) & 1u);   // RNE
    return (unsigned short)(u >> 16);
}
static __device__ __forceinline__ float bf2f(unsigned short b) {
    union { uint32_t u; float f; } v; v.u = ((uint32_t)b) << 16;
    return v.f;
}
static __device__ __forceinline__ bf16x8 as_bf16x8(us8 u) {
    return __builtin_bit_cast(bf16x8, u);
}
static __device__ __forceinline__ float signf_(float w) {
    return (w > 0.f) ? 1.f : ((w < 0.f) ? -1.f : 0.f);
}

typedef __attribute__((address_space(1))) void as1_void;
typedef __attribute__((address_space(3))) void as3_void;
static __device__ __forceinline__ void gload_lds16(const unsigned short* g, unsigned short* l) {
    // 16B per lane, wave-uniform LDS base + lane*16 (guide §5: width=16 verified m97)
    __builtin_amdgcn_global_load_lds((as1_void*)g, (as3_void*)l, 16, 0, 0);
}

// ---------------------------------------------------------------------------
// Weight prep: sign(w1) -> bf16 [L][D][CB]; sign(wd) -> f32 [L][D][3]
// ---------------------------------------------------------------------------
__global__ void prep_kernel(const float* __restrict__ w1, const float* __restrict__ wd,
                            unsigned short* __restrict__ W1S, float* __restrict__ WDS) {
    const int NW1 = NL * DCH * CBC;
    const int NWD = NL * DCH * KW;
    int idx = blockIdx.x * 256 + threadIdx.x;
    if (idx < NW1) {
        W1S[idx] = f2bf(signf_(w1[idx]));
    } else if (idx < NW1 + NWD) {
        int j = idx - NW1;
        WDS[j] = signf_(wd[j]);
    }
}

// ---------------------------------------------------------------------------
// Input transpose: x [B][CB][T] f32  ->  XA [B*T][CB] bf16
// ---------------------------------------------------------------------------
__global__ void transpose_in(const float* __restrict__ x, unsigned short* __restrict__ XA) {
    __shared__ unsigned short tile[64][72];
    const int t0 = blockIdx.x * 64, c0 = blockIdx.y * 64, b = blockIdx.z;
    const int tid = threadIdx.x;
    {
        const int cl = tid >> 2;
        const int tl = (tid & 3) * 16;
        const float* src = x + ((size_t)(b * CBC + c0 + cl)) * TT + t0 + tl;
        #pragma unroll
        for (int u = 0; u < 16; u += 4) {
            float4 f = *(const float4*)(src + u);
            tile[cl][tl + u + 0] = f2bf(f.x);
            tile[cl][tl + u + 1] = f2bf(f.y);
            tile[cl][tl + u + 2] = f2bf(f.z);
            tile[cl][tl + u + 3] = f2bf(f.w);
        }
    }
    __syncthreads();
    {
        const int tr = tid >> 2;
        const int cc = (tid & 3) * 16;
        us8 o0, o1;
        #pragma unroll
        for (int e = 0; e < 8; ++e) { o0[e] = tile[cc + e][tr]; o1[e] = tile[cc + 8 + e][tr]; }
        unsigned short* dst = XA + ((size_t)(b * TT + t0 + tr)) * CBC + c0 + cc;
        *(us8*)dst = o0;
        *(us8*)(dst + 8) = o1;
    }
}

// ---------------------------------------------------------------------------
// GEMM: out[n][m] = sum_k A[m][k] * B[n][k] (+bias, optional PReLU)
// ROUND-6 CONFIGURATION, REVERTED VERBATIM (measured best: GEMM1 49us,
// 2.8TB/s, total 581us). 128x128 tile, BK=32, 256 threads,
// __launch_bounds__(256,4) -> VGPR 68, LDS 34.8KB -> 4 blocks/CU.
// The r6-r9 series isolated blocks/CU TLP as the controlling variable for
// the 2-phase structure (4->49us, 3->50.6, 2->~51, 1->80): the per-iter
// stage+vmcnt(0)+barrier toll is hidden by OTHER resident blocks, and
// only this config reaches 4 blocks/CU. Retired levers: counted-vmcnt
// (r2 race, r7 null), 256-wide tile (r8 spill, r9 TLP loss).
// Catalog-verified 2-phase double-buffer (T3 minimum, m248v2): per iter
// {STAGE(next) -> ds_read(cur) -> MFMA -> vmcnt(0) -> s_barrier};
// sched_barrier(0) pins the schedule (rule #18). LDS XOR swizzle
// both-sides (rule #21). Grid: 1D, bijective XCD-chunked swizzle,
// m-tiles innermost (L2 B-reuse).
// ---------------------------------------------------------------------------
template<int K, int NMT, bool PRELU, bool FINAL, bool STATS>
__global__ __launch_bounds__(256, 4)
void gemm_kernel(const unsigned short* __restrict__ A,
                 const unsigned short* __restrict__ Bact,
                 const float* __restrict__ bias,
                 const float* __restrict__ aptr,
                 unsigned short* __restrict__ Obf,
                 float* __restrict__ Ofin,
                 const float* __restrict__ resid,
                 float* __restrict__ sums, float* __restrict__ sqs,
                 int M) {
    __shared__ union {
        unsigned short stage[2][4][2048];    // [buf][A0,A1,B0,B1][64 rows x 32] = 32KB
        unsigned short sout[128 * 136];      // epilogue transpose (34KB)
    } sm;
    __shared__ float sstat[2][4][64];        // [sum/sq][wave][ch_local]

    const int tid = threadIdx.x;

    // bijective XCD-chunked swizzle (nwg % 8 == 0 always here, m204)
    const int nwg = NMT * (TT / 128) * BATCH;
    const int orig = blockIdx.x;
    const int logical = (orig & 7) * (nwg >> 3) + (orig >> 3);
    const int mt = logical % NMT;            // m-tile innermost -> same-XCD B reuse
    const int rest = logical / NMT;
    const int tt = rest & 31;                // TT/128 = 32 t-tiles
    const int bz = rest >> 5;
    const int t0 = tt * 128;
    const int m0 = mt * 128;
    const size_t n0 = (size_t)bz * TT + t0;

    const int lane = tid & 63;
    const int w    = tid >> 6;
    const int wm = w & 1, wn = w >> 1;
    const int l16 = lane & 15, q = lane >> 4;

    // staging: thread tid covers half-tile row tid>>2, swizzled 16B chunk
    const int rS = tid >> 2;
    const int cS = ((tid & 3) ^ ((tid >> 3) & 3)) * 8;   // chunk ^ ((row>>1)&3)
    const unsigned short* gA0 = A + (size_t)(m0 + rS) * K + cS;
    const unsigned short* gA1 = A + (size_t)(m0 + 64 + rS) * K + cS;
    const unsigned short* gB0 = Bact + (n0 + rS) * K + cS;
    const unsigned short* gB1 = Bact + (n0 + 64 + rS) * K + cS;
    const int wofs = w << 9;                  // per-wave 512-short (1KB) slice

    auto STAGE = [&](int step, int buf) {
        const int k0 = step * 32;
        unsigned short* sb = &sm.stage[buf][0][0];
        gload_lds16(gA0 + k0, sb + 0 * 2048 + wofs);
        gload_lds16(gA1 + k0, sb + 1 * 2048 + wofs);
        gload_lds16(gB0 + k0, sb + 2 * 2048 + wofs);
        gload_lds16(gB1 + k0, sb + 3 * 2048 + wofs);
    };

    f32x4 acc[4][4];
    #pragma unroll
    for (int i = 0; i < 4; ++i)
        #pragma unroll
        for (int j = 0; j < 4; ++j)
            acc[i][j] = (f32x4){0.f, 0.f, 0.f, 0.f};

    // read-side swizzle: same XOR as write side; ((i*16+l16)>>1)&3 == (l16>>1)&3
    const int csw = (q ^ ((l16 >> 1) & 3)) << 3;

    constexpr int NK = K / 32;
    // prologue: stage tile 0, publish
    STAGE(0, 0);
    asm volatile("s_waitcnt vmcnt(0)" ::: "memory");
    __builtin_amdgcn_s_barrier();
    __builtin_amdgcn_sched_barrier(0);

    #pragma unroll
    for (int k = 0; k < NK; ++k) {
        const int cur = k & 1;
        // issue next-tile loads FIRST (latency hides under compute below).
        if (k + 1 < NK) STAGE(k + 1, cur ^ 1);
        const unsigned short* sb = &sm.stage[cur][0][0];
        bf16x8 af[4], bfv[4];
        #pragma unroll
        for (int i = 0; i < 4; ++i)
            af[i] = as_bf16x8(*(const us8*)(sb + wm * 2048 + (i * 16 + l16) * 32 + csw));
        #pragma unroll
        for (int j = 0; j < 4; ++j)
            bfv[j] = as_bf16x8(*(const us8*)(sb + (2 + wn) * 2048 + (j * 16 + l16) * 32 + csw));
        #pragma unroll
        for (int i = 0; i < 4; ++i)
            #pragma unroll
            for (int j = 0; j < 4; ++j)
                acc[i][j] = __builtin_amdgcn_mfma_f32_16x16x32_bf16(af[i], bfv[j], acc[i][j], 0, 0, 0);
        // publish next tile: own loads landed, then barrier => all waves' landed
        if (k + 1 < NK) {
            asm volatile("s_waitcnt vmcnt(0)" ::: "memory");
            __builtin_amdgcn_sched_barrier(0);
        }
        __builtin_amdgcn_s_barrier();
        __builtin_amdgcn_sched_barrier(0);
    }
    // loop's final barrier: all waves' last ds_reads retired, vmcnt drained
    // since iter NK-2 => sout (unioned with stage) safe to write.

    float alpha = 0.f;
    if constexpr (PRELU) alpha = aptr[0];

    if constexpr (FINAL) {
        #pragma unroll
        for (int i = 0; i < 4; ++i) {
            const int m_l = wm * 64 + i * 16 + q * 4;
            float bia[4];
            #pragma unroll
            for (int rg = 0; rg < 4; ++rg) bia[rg] = bias[m0 + m_l + rg];
            #pragma unroll
            for (int j = 0; j < 4; ++j) {
                const int n_l = wn * 64 + j * 16 + l16;
                const int t = t0 + n_l;
                #pragma unroll
                for (int rg = 0; rg < 4; ++rg) {
                    float v = acc[i][j][rg] + bia[rg];
                    size_t oidx = ((size_t)(bz * CBC + m0 + m_l + rg)) * TT + t;
                    Ofin[oidx] = v + resid[oidx];
                }
            }
        }
    } else {
        #pragma unroll
        for (int i = 0; i < 4; ++i) {
            const int m_l = wm * 64 + i * 16 + q * 4;
            float bia[4];
            #pragma unroll
            for (int rg = 0; rg < 4; ++rg) bia[rg] = bias[m0 + m_l + rg];
            #pragma unroll
            for (int j = 0; j < 4; ++j) {
                const int n_l = wn * 64 + j * 16 + l16;
                us4 pkv;
                #pragma unroll
                for (int rg = 0; rg < 4; ++rg) {
                    float v = acc[i][j][rg] + bia[rg];
                    if (PRELU) v = (v >= 0.f) ? v : alpha * v;
                    pkv[rg] = f2bf(v);
                }
                *(us4*)&sm.sout[n_l * 136 + m_l] = pkv;
            }
            if constexpr (STATS) {
                #pragma unroll
                for (int rg = 0; rg < 4; ++rg) {
                    float sv = 0.f, sq2 = 0.f;
                    #pragma unroll
                    for (int j = 0; j < 4; ++j) {
                        float v = acc[i][j][rg] + bia[rg];
                        if (PRELU) v = (v >= 0.f) ? v : alpha * v;
                        sv += v; sq2 += v * v;
                    }
                    #pragma unroll
                    for (int msk = 1; msk < 16; msk <<= 1) {
                        sv  += __shfl_xor(sv,  msk, 64);
                        sq2 += __shfl_xor(sq2, msk, 64);
                    }
                    if (l16 == 0) {
                        const int cl = i * 16 + q * 4 + rg;   // channel local to wm
                        sstat[0][w][cl] = sv;
                        sstat[1][w][cl] = sq2;
                    }
                }
            }
        }
        __syncthreads();
        const int rr = tid >> 4;
        const int c8 = (tid & 15) * 8;
        #pragma unroll
        for (int p = 0; p < 8; ++p) {
            const int n_l = p * 16 + rr;
            us8 v = *(const us8*)&sm.sout[n_l * 136 + c8];
            *(us8*)(Obf + (n0 + n_l) * M + m0 + c8) = v;
        }
        if constexpr (STATS) {
            if (tid < 128) {
                const int wmc = tid >> 6, cl = tid & 63;
                float S = sstat[0][wmc][cl] + sstat[0][wmc + 2][cl];
                float Q = sstat[1][wmc][cl] + sstat[1][wmc + 2][cl];
                atomicAdd(&sums[m0 + tid], S);
                atomicAdd(&sqs[m0 + tid], Q);
            }
        }
    }
}

// ---------------------------------------------------------------------------
// Depthwise dilated causal conv + bias + PReLU, fused Z-stats.
// UNCHANGED from round 6 (channel-split grid + 16B/lane us8 layout,
// verified). Steady blocks use the exact BN1 fold (wk in {+-1,0}).
// grid = (TT/64, 2, BATCH), block 256.
// ---------------------------------------------------------------------------
__global__ __launch_bounds__(256)
void dwconv_kernel(const unsigned short* __restrict__ Y,
                   const float* __restrict__ sums1, const float* __restrict__ sqs1,
                   const float* __restrict__ g1, const float* __restrict__ be1,
                   const float* __restrict__ wds, const float* __restrict__ bd,
                   const float* __restrict__ a2p, int dil,
                   unsigned short* __restrict__ Z,
                   float* __restrict__ sums2, float* __restrict__ sqs2) {
    __shared__ float ssum[4][256];
    __shared__ float ssq[4][256];
    const int b = blockIdx.z;
    const int half = blockIdx.y;
    const int t0 = blockIdx.x * 64;
    const int tid = threadIdx.x;
    const int w = tid >> 6;
    const int lane = tid & 63;
    const int r = lane >> 5;              // row sub-index within wave (0/1)
    const int cl = (lane & 31) * 8;       // channel local to this half
    const int c0 = half * 256 + cl;       // global channel base (8 channels)
    const float alpha = a2p[0];

    // fused BN1 finalize (per-lane, 8 channels) + raw weights
    float s8[8], sh8[8], wv0[8], wv1[8], wv2[8], bb8[8];
    const float inv = 1.f / (float)BT;
    #pragma unroll
    for (int e = 0; e < 8; ++e) {
        const int d = c0 + e;
        float mean = sums1[d] * inv;
        float var = sqs1[d] * inv - mean * mean;
        float sc = g1[d] * rsqrtf(var + EPSB);
        s8[e] = sc;
        sh8[e] = be1[d] - mean * sc;
        wv0[e] = wds[d * 3 + 0]; wv1[e] = wds[d * 3 + 1]; wv2[e] = wds[d * 3 + 2];
        bb8[e] = bd[d];
    }

    float asum[8], asq[8];
    #pragma unroll
    for (int e = 0; e < 8; ++e) { asum[e] = 0.f; asq[e] = 0.f; }

    if (blockIdx.x == 0) {
        // boundary block: conditional taps (t < 2*dil possible), unfolded BN
        for (int it = 0; it < 8; ++it) {
            const int t = it * 8 + 2 * w + r;
            const size_t base = ((size_t)b * TT + t) * DCH + c0;
            float acc[8];
            {
                us8 y0 = *(const us8*)&Y[base];
                #pragma unroll
                for (int e = 0; e < 8; ++e)
                    acc[e] = wv2[e] * (s8[e] * bf2f(y0[e]) + sh8[e]) + bb8[e];
            }
            if (t >= dil) {
                us8 y1 = *(const us8*)&Y[base - (size_t)dil * DCH];
                #pragma unroll
                for (int e = 0; e < 8; ++e)
                    acc[e] += wv1[e] * (s8[e] * bf2f(y1[e]) + sh8[e]);
            }
            if (t >= 2 * dil) {
                us8 y2 = *(const us8*)&Y[base - (size_t)(2 * dil) * DCH];
                #pragma unroll
                for (int e = 0; e < 8; ++e)
                    acc[e] += wv0[e] * (s8[e] * bf2f(y2[e]) + sh8[e]);
            }
            us8 o;
            #pragma unroll
            for (int e = 0; e < 8; ++e) {
                float v = acc[e];
                v = (v >= 0.f) ? v : alpha * v;
                asum[e] += v; asq[e] += v * v;
                o[e] = f2bf(v);
            }
            *(us8*)&Z[base] = o;
        }
    } else {
        // steady blocks: exact BN fold (w = +-1/0), unconditional taps
        float W0s[8], W1s[8], W2s[8], shall[8];
        #pragma unroll
        for (int e = 0; e < 8; ++e) {
            W0s[e] = wv0[e] * s8[e];
            W1s[e] = wv1[e] * s8[e];
            W2s[e] = wv2[e] * s8[e];
            shall[e] = (wv0[e] + wv1[e] + wv2[e]) * sh8[e] + bb8[e];
        }
        const size_t d1 = (size_t)dil * DCH, d2 = 2 * d1;
        for (int it = 0; it < 8; ++it) {
            const int t = t0 + it * 8 + 2 * w + r;
            const size_t base = ((size_t)b * TT + t) * DCH + c0;
            us8 y0 = *(const us8*)&Y[base];
            us8 y1 = *(const us8*)&Y[base - d1];
            us8 y2 = *(const us8*)&Y[base - d2];
            us8 o;
            #pragma unroll
            for (int e = 0; e < 8; ++e) {
                float v = W2s[e] * bf2f(y0[e]) + W1s[e] * bf2f(y1[e])
                        + W0s[e] * bf2f(y2[e]) + shall[e];
                v = (v >= 0.f) ? v : alpha * v;
                asum[e] += v; asq[e] += v * v;
                o[e] = f2bf(v);
            }
            *(us8*)&Z[base] = o;
        }
    }

    // combine the two row-groups (lane l and l+32 hold the same channels)
    #pragma unroll
    for (int e = 0; e < 8; ++e) {
        asum[e] += __shfl_xor(asum[e], 32, 64);
        asq[e]  += __shfl_xor(asq[e], 32, 64);
    }
    if (lane < 32) {
        #pragma unroll
        for (int e = 0; e < 8; ++e) { ssum[w][cl + e] = asum[e]; ssq[w][cl + e] = asq[e]; }
    }
    __syncthreads();
    {
        const int ch = tid;   // 0..255 (one channel per thread, local to half)
        float S = ssum[0][ch] + ssum[1][ch] + ssum[2][ch] + ssum[3][ch];
        float Q = ssq[0][ch] + ssq[1][ch] + ssq[2][ch] + ssq[3][ch];
        atomicAdd(&sums2[half * 256 + ch], S);
        atomicAdd(&sqs2[half * 256 + ch], Q);
    }
}

// ---------------------------------------------------------------------------
// Fold BN2 into GEMM2 weights (BN2 finalize fused in):
// sc2/shf2 computed per-thread from raw sums2/sqs2.
// W2eff[c][d] = sign(w2[c][d]) * sc2[d] (bf16)
// b2eff[c] = b2[c] + sum_d sign(w2[c][d]) * shf2[d]
// ---------------------------------------------------------------------------
__global__ void fold_kernel(const float* __restrict__ w2,
                            const float* __restrict__ sums2, const float* __restrict__ sqs2,
                            const float* __restrict__ g2, const float* __restrict__ be2,
                            const float* __restrict__ b2,
                            unsigned short* __restrict__ W2E, float* __restrict__ B2E) {
    __shared__ float red[256];
    const int c = blockIdx.x, tid = threadIdx.x;
    const float inv = 1.f / (float)BT;
    float part = 0.f;
    for (int d = tid; d < DCH; d += 256) {
        float mean = sums2[d] * inv;
        float var = sqs2[d] * inv - mean * mean;
        float sc = g2[d] * rsqrtf(var + EPSB);
        float shf = be2[d] - mean * sc;
        float w = w2[(size_t)c * DCH + d];
        float sgn = signf_(w);
        W2E[(size_t)c * DCH + d] = f2bf(sgn * sc);
        part += sgn * shf;
    }
    red[tid] = part;
    __syncthreads();
    for (int off = 128; off > 0; off >>= 1) {
        if (tid < off) red[tid] += red[tid + off];
        __syncthreads();
    }
    if (tid == 0) B2E[c] = b2[c] + red[0];
}

// ---------------------------------------------------------------------------
extern "C" void kernel_launch(void* const* d_in, const int* in_sizes, int n_in,
                              void* d_out, int out_size, void* d_ws, size_t ws_size,
                              hipStream_t stream) {
    const float* x   = (const float*)d_in[0];
    const float* w1  = (const float*)d_in[1];
    const float* b1  = (const float*)d_in[2];
    const float* a1  = (const float*)d_in[3];
    const float* g1  = (const float*)d_in[4];
    const float* be1 = (const float*)d_in[5];
    const float* wd  = (const float*)d_in[6];
    const float* bd  = (const float*)d_in[7];
    const float* a2  = (const float*)d_in[8];
    const float* g2  = (const float*)d_in[9];
    const float* be2 = (const float*)d_in[10];
    const float* w2  = (const float*)d_in[11];
    const float* b2  = (const float*)d_in[12];
    float* out = (float*)d_out;

    char* ws = (char*)d_ws;
    size_t off = 0;
    auto alloc = [&](size_t bytes) -> void* {
        void* p = ws + off;
        off += (bytes + 255) & ~(size_t)255;
        return p;
    };
    unsigned short* XA  = (unsigned short*)alloc((size_t)BT * CBC * 2);
    unsigned short* Y   = (unsigned short*)alloc((size_t)BT * DCH * 2);
    unsigned short* Z   = (unsigned short*)alloc((size_t)BT * DCH * 2);
    unsigned short* W1S = (unsigned short*)alloc((size_t)NL * DCH * CBC * 2);
    float* WDS          = (float*)alloc((size_t)NL * DCH * KW * 4);
    unsigned short* W2E = (unsigned short*)alloc((size_t)CBC * DCH * 2);
    float* B2E          = (float*)alloc((size_t)CBC * 4);
    // per-layer stat buffers: [sums1|sqs1|sums2|sqs2] x NL x 512, zeroed once
    float* stats = (float*)alloc((size_t)4 * NL * 512 * 4);
    float* sums1 = stats + 0 * NL * 512;
    float* sqs1  = stats + 1 * NL * 512;
    float* sums2 = stats + 2 * NL * 512;
    float* sqs2  = stats + 3 * NL * 512;

    (void)hipMemsetAsync(stats, 0, (size_t)4 * NL * 512 * 4, stream);

    {
        const int NTOT = NL * DCH * CBC + NL * DCH * KW;
        prep_kernel<<<(NTOT + 255) / 256, 256, 0, stream>>>(w1, wd, W1S, WDS);
    }
    transpose_in<<<dim3(TT / 64, CBC / 64, BATCH), 256, 0, stream>>>(x, XA);

    const int NWG1 = (DCH / 128) * (TT / 128) * BATCH;   // 4*32*16 = 2048
    const int NWG2 = (CBC / 128) * (TT / 128) * BATCH;   // 2*32*16 = 1024

    for (int l = 0; l < NL; ++l) {
        // 1x1 conv CB->D + bias + PReLU, fused BN1 stats
        gemm_kernel<CBC, DCH / 128, true, false, true><<<NWG1, 256, 0, stream>>>(
            W1S + (size_t)l * DCH * CBC, XA, b1 + (size_t)l * DCH, a1 + l,
            Y, nullptr, nullptr, sums1 + l * 512, sqs1 + l * 512, DCH);
        // depthwise dilated conv (BN1 finalize fused) + bias + PReLU, fused BN2 stats
        dwconv_kernel<<<dim3(TT / 64, 2, BATCH), 256, 0, stream>>>(
            Y, sums1 + l * 512, sqs1 + l * 512, g1 + (size_t)l * DCH, be1 + (size_t)l * DCH,
            WDS + (size_t)l * DCH * KW, bd + (size_t)l * DCH, a2 + l, 1 << l,
            Z, sums2 + l * 512, sqs2 + l * 512);
        // fold BN2 (finalize fused) into GEMM2 weights
        fold_kernel<<<CBC, 256, 0, stream>>>(w2 + (size_t)l * CBC * DCH,
                                             sums2 + l * 512, sqs2 + l * 512,
                                             g2 + (size_t)l * DCH, be2 + (size_t)l * DCH,
                                             b2 + (size_t)l * CBC, W2E, B2E);
        // 1x1 conv D->CB (+ residual & fp32 [B][CB][T] on final layer)
        if (l < NL - 1) {
            gemm_kernel<DCH, CBC / 128, false, false, false><<<NWG2, 256, 0, stream>>>(
                W2E, Z, B2E, nullptr, XA, nullptr, nullptr, nullptr, nullptr, CBC);
        } else {
            gemm_kernel<DCH, CBC / 128, false, true, false><<<NWG2, 256, 0, stream>>>(
                W2E, Z, B2E, nullptr, nullptr, out, x, nullptr, nullptr, CBC);
        }
    }
}